// Round 3
// baseline (798.698 us; speedup 1.0000x reference)
//
#include <hip/hip_runtime.h>
#include <stdint.h>
#include <type_traits>

typedef __attribute__((ext_vector_type(8))) short short8;
typedef __attribute__((ext_vector_type(4))) float f32x4;

#define S_LEN 4096
#define D_DIM 256
#define BATCH 4

__device__ __forceinline__ f32x4 mfma16(short8 a, short8 b, f32x4 c) {
    return __builtin_amdgcn_mfma_f32_16x16x32_bf16(a, b, c, 0, 0, 0);
}

// fp32 -> bf16 bits, round-to-nearest-even (matches numpy/ml_dtypes)
__device__ __forceinline__ short f2bf(float x) {
    uint32_t u = __float_as_uint(x);
    uint32_t r = (u + 0x7FFFu + ((u >> 16) & 1u)) >> 16;
    return (short)r;
}

__device__ __forceinline__ short8 load8(const short* p) {  // bf16 bits
    return *reinterpret_cast<const short8*>(p);
}
__device__ __forceinline__ short8 load8(const float* p) {  // fp32 -> bf16
    f32x4 a = *reinterpret_cast<const f32x4*>(p);
    f32x4 b = *reinterpret_cast<const f32x4*>(p + 4);
    short8 r;
#pragma unroll
    for (int i = 0; i < 4; ++i) r[i] = f2bf(a[i]);
#pragma unroll
    for (int i = 0; i < 4; ++i) r[i + 4] = f2bf(b[i]);
    return r;
}

// ---- transpose four 256x256 fp32 weights into bf16 ws (WT[z][f][d] = W[z][d][f]) ----
__global__ __launch_bounds__(256) void transpose_w(
    const float* __restrict__ wq, const float* __restrict__ wk,
    const float* __restrict__ wv, const float* __restrict__ wo,
    short* __restrict__ out)
{
    __shared__ float t[16][17];
    const float* in = blockIdx.z == 0 ? wq : blockIdx.z == 1 ? wk
                    : blockIdx.z == 2 ? wv : wo;
    short* o = out + (size_t)blockIdx.z * 65536;
    const int x0 = blockIdx.x * 16, y0 = blockIdx.y * 16;
    const int tx = threadIdx.x, ty = threadIdx.y;
    t[ty][tx] = in[(y0 + ty) * 256 + x0 + tx];
    __syncthreads();
    o[(size_t)(x0 + ty) * 256 + y0 + tx] = f2bf(t[tx][ty]);
}

// ---- C[M][N] = A[M][256] * Bt[N][256]^T (+bias fp32), fp32 accum ----
// TA/TB: short (bf16 bits) or float. TC: short (bf16) or float.
// bias_mode: 0 none, 1 bias[col], 2 bias[row]
template <typename TA, typename TB, typename TC>
__global__ __launch_bounds__(256) void gemm_bt(
    const TA* __restrict__ A, const TB* __restrict__ Bt,
    const float* __restrict__ bias, TC* __restrict__ C,
    int M, int N, int ldc, int bias_mode)
{
    const int K = 256;
    __shared__ short As[128 * 64];
    __shared__ short Bs[128 * 64];
    const int tid = threadIdx.x;
    const int lane = tid & 63;
    const int w = tid >> 6;
    const int wr = w >> 1, wc = w & 1;
    const int lo = lane & 15, hi = lane >> 4;
    const size_t m0 = (size_t)blockIdx.y * 128, n0 = (size_t)blockIdx.x * 128;

    f32x4 acc[4][4] = {};

    for (int kt = 0; kt < 4; ++kt) {
        short8 va[4], vb[4];
#pragma unroll
        for (int i = 0; i < 4; ++i) {
            int s = tid + 256 * i;                 // 16B(bf16) slot 0..1023
            int row = s >> 3, ke = (s & 7) * 8;    // 8 slots per 64-elem row
            va[i] = load8(A  + (m0 + row) * K + kt * 64 + ke);
            vb[i] = load8(Bt + (n0 + row) * K + kt * 64 + ke);
        }
#pragma unroll
        for (int i = 0; i < 4; ++i) {
            int s = tid + 256 * i;
            *reinterpret_cast<short8*>(&As[s * 8]) = va[i];
            *reinterpret_cast<short8*>(&Bs[s * 8]) = vb[i];
        }
        __syncthreads();
#pragma unroll
        for (int kk = 0; kk < 2; ++kk) {
            short8 af[4], bf[4];
#pragma unroll
            for (int m = 0; m < 4; ++m)
                af[m] = *reinterpret_cast<const short8*>(&As[(wr * 64 + m * 16 + lo) * 64 + kk * 32 + hi * 8]);
#pragma unroll
            for (int n = 0; n < 4; ++n)
                bf[n] = *reinterpret_cast<const short8*>(&Bs[(wc * 64 + n * 16 + lo) * 64 + kk * 32 + hi * 8]);
#pragma unroll
            for (int m = 0; m < 4; ++m)
#pragma unroll
                for (int n = 0; n < 4; ++n)
                    acc[m][n] = mfma16(af[m], bf[n], acc[m][n]);
        }
        __syncthreads();
    }

#pragma unroll
    for (int m = 0; m < 4; ++m) {
#pragma unroll
        for (int n = 0; n < 4; ++n) {
#pragma unroll
            for (int j = 0; j < 4; ++j) {
                size_t row = m0 + wr * 64 + m * 16 + hi * 4 + j;
                size_t col = n0 + wc * 64 + n * 16 + lo;
                float v = acc[m][n][j];
                if (bias_mode == 1)      v += bias[col];
                else if (bias_mode == 2) v += bias[row];
                if constexpr (std::is_same<TC, float>::value)
                    C[row * (size_t)ldc + col] = v;
                else
                    C[row * (size_t)ldc + col] = f2bf(v);
            }
        }
    }
}

// ---- causal flash attention: Sc = softmax(mask(Q K^T / 16)) V ----
// Q,K: [B*S][256] bf16; VT: [256][B*S] bf16; Sc: [B*S][256] bf16 (may alias Q)
__global__ __launch_bounds__(256) void attn_fwd(
    const short* __restrict__ Q, const short* __restrict__ Km,
    const short* __restrict__ VT, short* __restrict__ Sc)
{
    __shared__ short P[4][16 * 64];
    const int tid = threadIdx.x;
    const int lane = tid & 63;
    const int w = tid >> 6;
    const int lo = lane & 15, hi = lane >> 4;
    const int b = blockIdx.y;
    const int j0 = blockIdx.x * 4 + w;  // 16-row q-tile index, 0..127
    const short* Qb = Q  + (size_t)b * S_LEN * D_DIM;
    const short* Kb = Km + (size_t)b * S_LEN * D_DIM;
    const short* Vb = VT + (size_t)b * S_LEN;          // col offset; row stride B*S
    short* Sb = Sc + (size_t)b * S_LEN * D_DIM;

    for (int rep = 0; rep < 2; ++rep) {
        const int jt = rep ? 255 - j0 : j0;     // mirror pairing: causal load balance
        const int q0 = jt * 16;

        short8 qv[8];
#pragma unroll
        for (int kk = 0; kk < 8; ++kk)
            qv[kk] = *reinterpret_cast<const short8*>(Qb + (size_t)(q0 + lo) * D_DIM + kk * 32 + hi * 8);

        f32x4 o[16] = {};
        float mrow[4] = {-1e30f, -1e30f, -1e30f, -1e30f};
        float lrow[4] = {0.f, 0.f, 0.f, 0.f};

        const int nkt = (q0 >> 6) + 1;
        for (int kt = 0; kt < nkt; ++kt) {
            const int k0 = kt * 64;
            f32x4 s4[4] = {};
#pragma unroll
            for (int kk = 0; kk < 8; ++kk) {
#pragma unroll
                for (int n = 0; n < 4; ++n) {
                    short8 kf = *reinterpret_cast<const short8*>(
                        Kb + (size_t)(k0 + n * 16 + lo) * D_DIM + kk * 32 + hi * 8);
                    s4[n] = mfma16(qv[kk], kf, s4[n]);
                }
            }
            const bool diag = (kt == nkt - 1);
            float pm[4] = {-1e30f, -1e30f, -1e30f, -1e30f};
#pragma unroll
            for (int n = 0; n < 4; ++n) {
#pragma unroll
                for (int j = 0; j < 4; ++j) {
                    float v = s4[n][j] * 0.0625f;  // 1/sqrt(256)
                    if (diag) {
                        int r = q0 + hi * 4 + j, c = k0 + n * 16 + lo;
                        if (c > r) v = -1e30f;     // causal mask
                    }
                    s4[n][j] = v;
                    pm[j] = fmaxf(pm[j], v);
                }
            }
#pragma unroll
            for (int off = 1; off < 16; off <<= 1)
#pragma unroll
                for (int j = 0; j < 4; ++j)
                    pm[j] = fmaxf(pm[j], __shfl_xor(pm[j], off));

            float sc[4], lsum[4];
#pragma unroll
            for (int j = 0; j < 4; ++j) {
                float mn = fmaxf(mrow[j], pm[j]);
                sc[j] = __expf(mrow[j] - mn);
                mrow[j] = mn;
                lsum[j] = 0.f;
            }
#pragma unroll
            for (int n = 0; n < 4; ++n)
#pragma unroll
                for (int j = 0; j < 4; ++j) {
                    float p = __expf(s4[n][j] - mrow[j]);
                    s4[n][j] = p;
                    lsum[j] += p;
                }
#pragma unroll
            for (int off = 1; off < 16; off <<= 1)
#pragma unroll
                for (int j = 0; j < 4; ++j)
                    lsum[j] += __shfl_xor(lsum[j], off);
#pragma unroll
            for (int j = 0; j < 4; ++j)
                lrow[j] = lrow[j] * sc[j] + lsum[j];
#pragma unroll
            for (int nf = 0; nf < 16; ++nf)
#pragma unroll
                for (int j = 0; j < 4; ++j)
                    o[nf][j] *= sc[j];

            // P (fp32, C/D layout) -> LDS -> A-frag layout (bf16)
#pragma unroll
            for (int n = 0; n < 4; ++n)
#pragma unroll
                for (int j = 0; j < 4; ++j)
                    P[w][(hi * 4 + j) * 64 + n * 16 + lo] = f2bf(s4[n][j]);

#pragma unroll
            for (int k2 = 0; k2 < 2; ++k2) {
                short8 pa = *reinterpret_cast<const short8*>(&P[w][lo * 64 + k2 * 32 + hi * 8]);
#pragma unroll
                for (int nf = 0; nf < 16; ++nf) {
                    short8 vf = *reinterpret_cast<const short8*>(
                        Vb + (size_t)(nf * 16 + lo) * (BATCH * S_LEN) + k0 + k2 * 32 + hi * 8);
                    o[nf] = mfma16(pa, vf, o[nf]);
                }
            }
        }

#pragma unroll
        for (int nf = 0; nf < 16; ++nf)
#pragma unroll
            for (int j = 0; j < 4; ++j) {
                size_t row = q0 + hi * 4 + j;
                size_t col = nf * 16 + lo;
                Sb[row * D_DIM + col] = f2bf(o[nf][j] / lrow[j]);
            }
    }
}

extern "C" void kernel_launch(void* const* d_in, const int* in_sizes, int n_in,
                              void* d_out, int out_size, void* d_ws, size_t ws_size,
                              hipStream_t stream)
{
    const float* x  = (const float*)d_in[0];
    // d_in[1] = mask (int32 tril) — causality applied analytically, not read
    const float* wq = (const float*)d_in[2];
    const float* bq = (const float*)d_in[3];
    const float* wk = (const float*)d_in[4];
    const float* bk = (const float*)d_in[5];
    const float* wv = (const float*)d_in[6];
    const float* bv = (const float*)d_in[7];
    const float* wo = (const float*)d_in[8];
    const float* bo = (const float*)d_in[9];
    float* out = (float*)d_out;

    const size_t NTOK = (size_t)BATCH * S_LEN;          // 16384
    short* WT  = (short*)d_ws;                          // 4 * 65536 bf16
    short* Qw  = WT + 4 * 65536;
    short* Kw  = Qw + NTOK * D_DIM;
    short* VTw = Kw + NTOK * D_DIM;
    short* Sw  = Qw;   // alias: rep0 writes S rows [0,2048) which no later Q-read touches;
                       // rep1 reads Q rows [2048,4096) before writing those same rows itself.

    const int M = (int)NTOK;

    transpose_w<<<dim3(16, 16, 4), dim3(16, 16), 0, stream>>>(wq, wk, wv, wo, WT);
    // Q = x WqT^T + bq ; K = x WkT^T + bk
    gemm_bt<float, short, short><<<dim3(2, M / 128), 256, 0, stream>>>(x, WT,         bq, Qw, M, 256, 256, 1);
    gemm_bt<float, short, short><<<dim3(2, M / 128), 256, 0, stream>>>(x, WT + 65536, bk, Kw, M, 256, 256, 1);
    // VT[f][m] = sum_d WvT[f][d] x[m][d] + bv[f]  (V stored transposed)
    gemm_bt<short, float, short><<<dim3(M / 128, 2), 256, 0, stream>>>(WT + 2 * 65536, x, bv, VTw, 256, M, M, 2);
    attn_fwd<<<dim3(S_LEN / 128, BATCH), 256, 0, stream>>>(Qw, Kw, VTw, Sw);
    // out = Sc WoT^T + bo
    gemm_bt<short, short, float><<<dim3(2, M / 128), 256, 0, stream>>>(Sw, WT + 3 * 65536, bo, out, M, 256, 256, 1);
}

// Round 4
// 382.045 us; speedup vs baseline: 2.0906x; 2.0906x over previous
//
#include <hip/hip_runtime.h>
#include <stdint.h>
#include <type_traits>

typedef __attribute__((ext_vector_type(8))) short short8;
typedef __attribute__((ext_vector_type(4))) float f32x4;

#define S_LEN 4096
#define D_DIM 256
#define BATCH 4

__device__ __forceinline__ f32x4 mfma16(short8 a, short8 b, f32x4 c) {
    return __builtin_amdgcn_mfma_f32_16x16x32_bf16(a, b, c, 0, 0, 0);
}

// fp32 -> bf16 bits, round-to-nearest-even (matches numpy/ml_dtypes)
__device__ __forceinline__ short f2bf(float x) {
    uint32_t u = __float_as_uint(x);
    uint32_t r = (u + 0x7FFFu + ((u >> 16) & 1u)) >> 16;
    return (short)r;
}

__device__ __forceinline__ short8 load8(const short* p) {  // bf16 bits
    return *reinterpret_cast<const short8*>(p);
}
__device__ __forceinline__ short8 load8(const float* p) {  // fp32 -> bf16
    f32x4 a = *reinterpret_cast<const f32x4*>(p);
    f32x4 b = *reinterpret_cast<const f32x4*>(p + 4);
    short8 r;
#pragma unroll
    for (int i = 0; i < 4; ++i) r[i] = f2bf(a[i]);
#pragma unroll
    for (int i = 0; i < 4; ++i) r[i + 4] = f2bf(b[i]);
    return r;
}

// ---- transpose four 256x256 fp32 weights into bf16 ws (WT[z][f][d] = W[z][d][f]) ----
__global__ __launch_bounds__(256) void transpose_w(
    const float* __restrict__ wq, const float* __restrict__ wk,
    const float* __restrict__ wv, const float* __restrict__ wo,
    short* __restrict__ out)
{
    __shared__ float t[16][17];
    const float* in = blockIdx.z == 0 ? wq : blockIdx.z == 1 ? wk
                    : blockIdx.z == 2 ? wv : wo;
    short* o = out + (size_t)blockIdx.z * 65536;
    const int x0 = blockIdx.x * 16, y0 = blockIdx.y * 16;
    const int tx = threadIdx.x, ty = threadIdx.y;
    t[ty][tx] = in[(y0 + ty) * 256 + x0 + tx];
    __syncthreads();
    o[(size_t)(x0 + ty) * 256 + y0 + tx] = f2bf(t[tx][ty]);
}

// ---- C[M][N] = A[M][256] * Bt[N][256]^T (+bias fp32), fp32 accum ----
// bias_mode: 0 none, 1 bias[col], 2 bias[row]
template <typename TA, typename TB, typename TC>
__global__ __launch_bounds__(256) void gemm_bt(
    const TA* __restrict__ A, const TB* __restrict__ Bt,
    const float* __restrict__ bias, TC* __restrict__ C,
    int M, int N, int ldc, int bias_mode)
{
    const int K = 256;
    __shared__ short As[128 * 64];
    __shared__ short Bs[128 * 64];
    const int tid = threadIdx.x;
    const int lane = tid & 63;
    const int w = tid >> 6;
    const int wr = w >> 1, wc = w & 1;
    const int lo = lane & 15, hi = lane >> 4;
    const size_t m0 = (size_t)blockIdx.y * 128, n0 = (size_t)blockIdx.x * 128;

    f32x4 acc[4][4] = {};

    for (int kt = 0; kt < 4; ++kt) {
        short8 va[4], vb[4];
#pragma unroll
        for (int i = 0; i < 4; ++i) {
            int s = tid + 256 * i;                 // 16B(bf16) slot 0..1023
            int row = s >> 3, ke = (s & 7) * 8;    // 8 slots per 64-elem row
            va[i] = load8(A  + (m0 + row) * K + kt * 64 + ke);
            vb[i] = load8(Bt + (n0 + row) * K + kt * 64 + ke);
        }
#pragma unroll
        for (int i = 0; i < 4; ++i) {
            int s = tid + 256 * i;
            *reinterpret_cast<short8*>(&As[s * 8]) = va[i];
            *reinterpret_cast<short8*>(&Bs[s * 8]) = vb[i];
        }
        __syncthreads();
#pragma unroll
        for (int kk = 0; kk < 2; ++kk) {
            short8 af[4], bf[4];
#pragma unroll
            for (int m = 0; m < 4; ++m)
                af[m] = *reinterpret_cast<const short8*>(&As[(wr * 64 + m * 16 + lo) * 64 + kk * 32 + hi * 8]);
#pragma unroll
            for (int n = 0; n < 4; ++n)
                bf[n] = *reinterpret_cast<const short8*>(&Bs[(wc * 64 + n * 16 + lo) * 64 + kk * 32 + hi * 8]);
#pragma unroll
            for (int m = 0; m < 4; ++m)
#pragma unroll
                for (int n = 0; n < 4; ++n)
                    acc[m][n] = mfma16(af[m], bf[n], acc[m][n]);
        }
        __syncthreads();
    }

#pragma unroll
    for (int m = 0; m < 4; ++m) {
#pragma unroll
        for (int n = 0; n < 4; ++n) {
#pragma unroll
            for (int j = 0; j < 4; ++j) {
                size_t row = m0 + wr * 64 + m * 16 + hi * 4 + j;
                size_t col = n0 + wc * 64 + n * 16 + lo;
                float v = acc[m][n][j];
                if (bias_mode == 1)      v += bias[col];
                else if (bias_mode == 2) v += bias[row];
                if constexpr (std::is_same<TC, float>::value)
                    C[row * (size_t)ldc + col] = v;
                else
                    C[row * (size_t)ldc + col] = f2bf(v);
            }
        }
    }
}

// ---- causal flash attention, in-block split-K ----
// Block = 4 waves, ONE 16-row q-tile. Wave w handles k-tiles w, w+4, w+8, ...
// LDS tree merge of the 4 online-softmax partials; wave 0 writes output.
// Q,K: [B*S][256] bf16; VT: [256][B*S] bf16; Sc: [B*S][256] bf16 (may alias Q)
__global__ __launch_bounds__(256) void attn_fwd(
    const short* __restrict__ Q, const short* __restrict__ Km,
    const short* __restrict__ VT, short* __restrict__ Sc)
{
    __shared__ short P[4][16 * 64];
    __shared__ float OB[2][16][260];     // padded: bank = 4*row + col%... 2-way max
    __shared__ float MLm[2][16], MLl[2][16];

    const int tid = threadIdx.x;
    const int lane = tid & 63;
    const int w = tid >> 6;
    const int lo = lane & 15, hi = lane >> 4;
    const int b = blockIdx.y;
    const int jt = 255 - (int)blockIdx.x;   // longest tiles first (LPT packing)
    const int q0 = jt * 16;
    const short* Qb = Q  + (size_t)b * S_LEN * D_DIM;
    const short* Kb = Km + (size_t)b * S_LEN * D_DIM;
    const short* Vb = VT + (size_t)b * S_LEN;          // col offset; row stride B*S
    short* Sb = Sc + (size_t)b * S_LEN * D_DIM;

    short8 qv[8];
#pragma unroll
    for (int kk = 0; kk < 8; ++kk)
        qv[kk] = *reinterpret_cast<const short8*>(Qb + (size_t)(q0 + lo) * D_DIM + kk * 32 + hi * 8);

    f32x4 o[16] = {};
    float mrow[4] = {-1e30f, -1e30f, -1e30f, -1e30f};
    float lrow[4] = {0.f, 0.f, 0.f, 0.f};

    const int nkt = (q0 >> 6) + 1;
    for (int kt = w; kt < nkt; kt += 4) {
        const int k0 = kt * 64;
        f32x4 s4[4] = {};
#pragma unroll
        for (int kk = 0; kk < 8; ++kk) {
#pragma unroll
            for (int n = 0; n < 4; ++n) {
                short8 kf = *reinterpret_cast<const short8*>(
                    Kb + (size_t)(k0 + n * 16 + lo) * D_DIM + kk * 32 + hi * 8);
                s4[n] = mfma16(qv[kk], kf, s4[n]);
            }
        }
        const bool diag = (kt == nkt - 1);
        float pm[4] = {-1e30f, -1e30f, -1e30f, -1e30f};
#pragma unroll
        for (int n = 0; n < 4; ++n) {
#pragma unroll
            for (int j = 0; j < 4; ++j) {
                float v = s4[n][j] * 0.0625f;  // 1/sqrt(256)
                if (diag) {
                    int r = q0 + hi * 4 + j, c = k0 + n * 16 + lo;
                    if (c > r) v = -1e30f;     // causal mask
                }
                s4[n][j] = v;
                pm[j] = fmaxf(pm[j], v);
            }
        }
#pragma unroll
        for (int off = 1; off < 16; off <<= 1)
#pragma unroll
            for (int j = 0; j < 4; ++j)
                pm[j] = fmaxf(pm[j], __shfl_xor(pm[j], off));

        float sc[4], lsum[4];
#pragma unroll
        for (int j = 0; j < 4; ++j) {
            float mn = fmaxf(mrow[j], pm[j]);
            sc[j] = __expf(mrow[j] - mn);
            mrow[j] = mn;
            lsum[j] = 0.f;
        }
#pragma unroll
        for (int n = 0; n < 4; ++n)
#pragma unroll
            for (int j = 0; j < 4; ++j) {
                float p = __expf(s4[n][j] - mrow[j]);
                s4[n][j] = p;
                lsum[j] += p;
            }
#pragma unroll
        for (int off = 1; off < 16; off <<= 1)
#pragma unroll
            for (int j = 0; j < 4; ++j)
                lsum[j] += __shfl_xor(lsum[j], off);
#pragma unroll
        for (int j = 0; j < 4; ++j)
            lrow[j] = lrow[j] * sc[j] + lsum[j];
#pragma unroll
        for (int nf = 0; nf < 16; ++nf)
#pragma unroll
            for (int j = 0; j < 4; ++j)
                o[nf][j] *= sc[j];

        // P (fp32, C/D layout) -> LDS -> A-frag layout (bf16)
#pragma unroll
        for (int n = 0; n < 4; ++n)
#pragma unroll
            for (int j = 0; j < 4; ++j)
                P[w][(hi * 4 + j) * 64 + n * 16 + lo] = f2bf(s4[n][j]);

#pragma unroll
        for (int k2 = 0; k2 < 2; ++k2) {
            short8 pa = *reinterpret_cast<const short8*>(&P[w][lo * 64 + k2 * 32 + hi * 8]);
#pragma unroll
            for (int nf = 0; nf < 16; ++nf) {
                short8 vf = *reinterpret_cast<const short8*>(
                    Vb + (size_t)(nf * 16 + lo) * (BATCH * S_LEN) + k0 + k2 * 32 + hi * 8);
                o[nf] = mfma16(pa, vf, o[nf]);
            }
        }
    }

    // ---- tree merge of 4 per-wave partials ----
    // round 1: waves 2,3 publish -> buf 0,1; waves 0,1 consume
    if (w >= 2) {
        int buf = w - 2;
#pragma unroll
        for (int nf = 0; nf < 16; ++nf)
#pragma unroll
            for (int j = 0; j < 4; ++j)
                OB[buf][hi * 4 + j][nf * 16 + lo] = o[nf][j];
        if (lo == 0)
#pragma unroll
            for (int j = 0; j < 4; ++j) {
                MLm[buf][hi * 4 + j] = mrow[j];
                MLl[buf][hi * 4 + j] = lrow[j];
            }
    }
    __syncthreads();
    if (w < 2) {
        int buf = w;
        float sa[4], sb[4];
#pragma unroll
        for (int j = 0; j < 4; ++j) {
            float mb = MLm[buf][hi * 4 + j];
            float lb = MLl[buf][hi * 4 + j];
            float M = fmaxf(mrow[j], mb);
            sa[j] = __expf(mrow[j] - M);
            sb[j] = __expf(mb - M);
            mrow[j] = M;
            lrow[j] = lrow[j] * sa[j] + lb * sb[j];
        }
#pragma unroll
        for (int nf = 0; nf < 16; ++nf)
#pragma unroll
            for (int j = 0; j < 4; ++j)
                o[nf][j] = o[nf][j] * sa[j] + OB[buf][hi * 4 + j][nf * 16 + lo] * sb[j];
    }
    __syncthreads();
    // round 2: wave 1 publishes -> buf 0; wave 0 consumes + writes out
    if (w == 1) {
#pragma unroll
        for (int nf = 0; nf < 16; ++nf)
#pragma unroll
            for (int j = 0; j < 4; ++j)
                OB[0][hi * 4 + j][nf * 16 + lo] = o[nf][j];
        if (lo == 0)
#pragma unroll
            for (int j = 0; j < 4; ++j) {
                MLm[0][hi * 4 + j] = mrow[j];
                MLl[0][hi * 4 + j] = lrow[j];
            }
    }
    __syncthreads();
    if (w == 0) {
        float sa[4], sb[4];
#pragma unroll
        for (int j = 0; j < 4; ++j) {
            float mb = MLm[0][hi * 4 + j];
            float lb = MLl[0][hi * 4 + j];
            float M = fmaxf(mrow[j], mb);
            sa[j] = __expf(mrow[j] - M);
            sb[j] = __expf(mb - M);
            lrow[j] = lrow[j] * sa[j] + lb * sb[j];
        }
#pragma unroll
        for (int nf = 0; nf < 16; ++nf)
#pragma unroll
            for (int j = 0; j < 4; ++j) {
                float v = (o[nf][j] * sa[j] + OB[0][hi * 4 + j][nf * 16 + lo] * sb[j]) / lrow[j];
                size_t row = q0 + hi * 4 + j;
                size_t col = nf * 16 + lo;
                Sb[row * D_DIM + col] = f2bf(v);
            }
    }
}

extern "C" void kernel_launch(void* const* d_in, const int* in_sizes, int n_in,
                              void* d_out, int out_size, void* d_ws, size_t ws_size,
                              hipStream_t stream)
{
    const float* x  = (const float*)d_in[0];
    // d_in[1] = mask (int32 tril) — causality applied analytically, not read
    const float* wq = (const float*)d_in[2];
    const float* bq = (const float*)d_in[3];
    const float* wk = (const float*)d_in[4];
    const float* bk = (const float*)d_in[5];
    const float* wv = (const float*)d_in[6];
    const float* bv = (const float*)d_in[7];
    const float* wo = (const float*)d_in[8];
    const float* bo = (const float*)d_in[9];
    float* out = (float*)d_out;

    const size_t NTOK = (size_t)BATCH * S_LEN;          // 16384
    short* WT  = (short*)d_ws;                          // 4 * 65536 bf16
    short* Qw  = WT + 4 * 65536;
    short* Kw  = Qw + NTOK * D_DIM;
    short* VTw = Kw + NTOK * D_DIM;
    short* Sw  = Qw;   // alias: each attn block reads only its own Q rows, then writes
                       // the same S rows — no cross-tile Q reads, safe in any order.

    const int M = (int)NTOK;

    transpose_w<<<dim3(16, 16, 4), dim3(16, 16), 0, stream>>>(wq, wk, wv, wo, WT);
    // Q = x WqT^T + bq ; K = x WkT^T + bk
    gemm_bt<float, short, short><<<dim3(2, M / 128), 256, 0, stream>>>(x, WT,         bq, Qw, M, 256, 256, 1);
    gemm_bt<float, short, short><<<dim3(2, M / 128), 256, 0, stream>>>(x, WT + 65536, bk, Kw, M, 256, 256, 1);
    // VT[f][m] = sum_d WvT[f][d] x[m][d] + bv[f]  (V stored transposed)
    gemm_bt<short, float, short><<<dim3(M / 128, 2), 256, 0, stream>>>(WT + 2 * 65536, x, bv, VTw, 256, M, M, 2);
    attn_fwd<<<dim3(256, BATCH), 256, 0, stream>>>(Qw, Kw, VTw, Sw);
    // out = Sc WoT^T + bo
    gemm_bt<short, short, float><<<dim3(2, M / 128), 256, 0, stream>>>(Sw, WT + 3 * 65536, bo, out, M, 256, 256, 1);
}